// Round 2
// baseline (98.605 us; speedup 1.0000x reference)
//
#include <hip/hip_runtime.h>
#include <math.h>

// Problem constants (x: (5,1,256,64,64) f32)
constexpr int NIMG = 5;
constexpr int CCH  = 256;   // channels (both c and d)
constexpr int HWP  = 4096;  // H*W
constexpr int PT   = CCH * HWP;  // pixels per image = 1048576

// GEMM tiling
constexpr int BD = 64;    // d-tile
constexpr int BP = 128;   // p-tile
constexpr int BK = 32;    // K-step

// -----------------------------------------------------------------------------
// Kernel 1: per-image channel-mixing GEMM producing
//   u[n,d,p] = x[n,d,p] - sum_c x[n,c,p]*(W1+W2)[c,d] - b[d]
//   v[n,d,p] = sum_c x[n,c,p]*W2[c,d]
// Tile: 64 d x 128 p per block, K-step 32, 256 threads, 4d x 8p micro-tile.
// LDS = 32 KB/block -> 5 blocks/CU. 0.5 B/FLOP LDS intensity (was 0.75).
// Accumulation order over c is IDENTICAL to the previous passing version
// (sequential c = 0..255, same fma chain) -> u,v bit-identical.
// -----------------------------------------------------------------------------
__global__ __launch_bounds__(256) void uv_gemm(
    const float* __restrict__ x, const float* __restrict__ w,
    const float* __restrict__ bias, float* __restrict__ u, float* __restrict__ v)
{
    const int t  = threadIdx.x;
    const int tp = t & 15;   // p-group: owns cols tp*4..+3 and 64+tp*4..+3
    const int td = t >> 4;   // d-group 0..15: owns rows td*4..+3
    const int p0 = blockIdx.x * BP;
    const int d0 = blockIdx.y * BD;
    const int n  = blockIdx.z;
    const float* xn = x + (size_t)n * PT;

    __shared__ float xs [BK][BP];  // 16 KB
    __shared__ float wss[BK][BD];  // 8 KB  (W1+W2)
    __shared__ float w2s[BK][BD];  // 8 KB  (W2)

    float acc_s[4][8] = {};  // sum_c x*(W1+W2)
    float acc_2[4][8] = {};  // sum_c x*W2

    for (int c0 = 0; c0 < CCH; c0 += BK) {
        // stage x tile: 32 rows x 128 cols = 1024 float4, 4 per thread
        #pragma unroll
        for (int k = 0; k < 4; ++k) {
            const int id = t + k * 256;
            const int r  = id >> 5;
            const int c4 = (id & 31) * 4;
            *reinterpret_cast<float4*>(&xs[r][c4]) =
                *reinterpret_cast<const float4*>(&xn[(size_t)(c0 + r) * HWP + p0 + c4]);
        }
        // stage weight tiles: 32 rows x 64 cols = 512 float4 each, 2 per thread
        #pragma unroll
        for (int k = 0; k < 2; ++k) {
            const int id = t + k * 256;
            const int r  = id >> 4;
            const int c4 = (id & 15) * 4;
            const float4 w1v = *reinterpret_cast<const float4*>(
                &w[(size_t)(c0 + r) * CCH + d0 + c4]);
            const float4 w2v = *reinterpret_cast<const float4*>(
                &w[(size_t)(256 + c0 + r) * CCH + d0 + c4]);
            *reinterpret_cast<float4*>(&w2s[r][c4]) = w2v;
            const float4 wsv = {w1v.x + w2v.x, w1v.y + w2v.y,
                                w1v.z + w2v.z, w1v.w + w2v.w};
            *reinterpret_cast<float4*>(&wss[r][c4]) = wsv;
        }
        __syncthreads();

        #pragma unroll 8
        for (int cc = 0; cc < BK; ++cc) {
            const float4 xv0 = *reinterpret_cast<const float4*>(&xs[cc][tp * 4]);
            const float4 xv1 = *reinterpret_cast<const float4*>(&xs[cc][64 + tp * 4]);
            const float4 wsv = *reinterpret_cast<const float4*>(&wss[cc][td * 4]);
            const float4 w2v = *reinterpret_cast<const float4*>(&w2s[cc][td * 4]);
            const float xa [8] = {xv0.x, xv0.y, xv0.z, xv0.w,
                                  xv1.x, xv1.y, xv1.z, xv1.w};
            const float wsa[4] = {wsv.x, wsv.y, wsv.z, wsv.w};
            const float w2a[4] = {w2v.x, w2v.y, w2v.z, w2v.w};
            #pragma unroll
            for (int i = 0; i < 4; ++i) {
                #pragma unroll
                for (int j = 0; j < 8; ++j) {
                    acc_s[i][j] = fmaf(wsa[i], xa[j], acc_s[i][j]);
                    acc_2[i][j] = fmaf(w2a[i], xa[j], acc_2[i][j]);
                }
            }
        }
        __syncthreads();
    }

    // Epilogue: u = x - acc_s - b[d], v = acc_2
    #pragma unroll
    for (int i = 0; i < 4; ++i) {
        const int d = d0 + td * 4 + i;
        const float bd = bias[d];
        const size_t base = (size_t)d * HWP + p0 + tp * 4;
        const float4 xv0 = *reinterpret_cast<const float4*>(&xn[base]);
        const float4 xv1 = *reinterpret_cast<const float4*>(&xn[base + 64]);
        float4 uo0, uo1, vo0, vo1;
        uo0.x = xv0.x - acc_s[i][0] - bd;
        uo0.y = xv0.y - acc_s[i][1] - bd;
        uo0.z = xv0.z - acc_s[i][2] - bd;
        uo0.w = xv0.w - acc_s[i][3] - bd;
        uo1.x = xv1.x - acc_s[i][4] - bd;
        uo1.y = xv1.y - acc_s[i][5] - bd;
        uo1.z = xv1.z - acc_s[i][6] - bd;
        uo1.w = xv1.w - acc_s[i][7] - bd;
        vo0.x = acc_2[i][0]; vo0.y = acc_2[i][1];
        vo0.z = acc_2[i][2]; vo0.w = acc_2[i][3];
        vo1.x = acc_2[i][4]; vo1.y = acc_2[i][5];
        vo1.z = acc_2[i][6]; vo1.w = acc_2[i][7];
        *reinterpret_cast<float4*>(&u[(size_t)n * PT + base])      = uo0;
        *reinterpret_cast<float4*>(&u[(size_t)n * PT + base + 64]) = uo1;
        *reinterpret_cast<float4*>(&v[(size_t)n * PT + base])      = vo0;
        *reinterpret_cast<float4*>(&v[(size_t)n * PT + base + 64]) = vo1;
    }
}

// -----------------------------------------------------------------------------
// Kernel 2: per-pixel 5x5 edge matrix e[i][j] = |u[j]-v[i]|, row-norm over j,
// threshold e/max(norm,1e-12) > 0.35, out[i] = sum_j kept_e * x[j].
// UNCHANGED from passing version (bit-identical output).
// -----------------------------------------------------------------------------
__global__ __launch_bounds__(256) void edge_out(
    const float* __restrict__ x, const float* __restrict__ u,
    const float* __restrict__ v, float* __restrict__ out)
{
    const size_t p = ((size_t)blockIdx.x * blockDim.x + threadIdx.x) * 4;
    if (p >= (size_t)PT) return;

    float xa[NIMG][4], ua[NIMG][4], va[NIMG][4];
    #pragma unroll
    for (int n2 = 0; n2 < NIMG; ++n2) {
        const float4 xv = *reinterpret_cast<const float4*>(&x[(size_t)n2 * PT + p]);
        const float4 uv = *reinterpret_cast<const float4*>(&u[(size_t)n2 * PT + p]);
        const float4 vv = *reinterpret_cast<const float4*>(&v[(size_t)n2 * PT + p]);
        xa[n2][0] = xv.x; xa[n2][1] = xv.y; xa[n2][2] = xv.z; xa[n2][3] = xv.w;
        ua[n2][0] = uv.x; ua[n2][1] = uv.y; ua[n2][2] = uv.z; ua[n2][3] = uv.w;
        va[n2][0] = vv.x; va[n2][1] = vv.y; va[n2][2] = vv.z; va[n2][3] = vv.w;
    }

    float oacc[NIMG][4];
    #pragma unroll
    for (int c = 0; c < 4; ++c) {
        #pragma unroll
        for (int i = 0; i < NIMG; ++i) {
            float e[NIMG];
            float sumsq = 0.0f;
            #pragma unroll
            for (int j = 0; j < NIMG; ++j) {
                e[j] = fabsf(ua[j][c] - va[i][c]);
                sumsq = fmaf(e[j], e[j], sumsq);
            }
            const float m = fmaxf(sqrtf(sumsq), 1e-12f);
            float h = 0.0f;
            #pragma unroll
            for (int j = 0; j < NIMG; ++j) {
                const float en = e[j] / m;
                if (en > 0.35f) h = fmaf(e[j], xa[j][c], h);
            }
            oacc[i][c] = h;
        }
    }

    #pragma unroll
    for (int i = 0; i < NIMG; ++i) {
        float4 ov = {oacc[i][0], oacc[i][1], oacc[i][2], oacc[i][3]};
        *reinterpret_cast<float4*>(&out[(size_t)i * PT + p]) = ov;
    }
}

extern "C" void kernel_launch(void* const* d_in, const int* in_sizes, int n_in,
                              void* d_out, int out_size, void* d_ws, size_t ws_size,
                              hipStream_t stream) {
    const float* x    = (const float*)d_in[0];
    const float* w    = (const float*)d_in[1];
    const float* bias = (const float*)d_in[2];
    float* out = (float*)d_out;

    float* u = (float*)d_ws;                       // 20 MB
    float* v = u + (size_t)NIMG * PT;              // 20 MB

    dim3 g1(HWP / BP, CCH / BD, NIMG);             // 32 x 4 x 5 = 640 blocks
    uv_gemm<<<g1, 256, 0, stream>>>(x, w, bias, u, v);

    const int n4 = PT / 4;                         // 262144 float4 pixels
    edge_out<<<(n4 + 255) / 256, 256, 0, stream>>>(x, u, v, out);
}